// Round 7
// baseline (183.149 us; speedup 1.0000x reference)
//
#include <hip/hip_runtime.h>
#include <hip/hip_bf16.h>

#define N 2048

using f32x2  = __attribute__((ext_vector_type(2))) float;
using f32x4  = __attribute__((ext_vector_type(4))) float;
using short8 = __attribute__((ext_vector_type(8))) short;
using uint4v = __attribute__((ext_vector_type(4))) unsigned int;

// async global->LDS, 16B per lane; LDS dest = wave-uniform base + lane*16
#define GLOAD_LDS16(dst, src)                                                        \
  __builtin_amdgcn_global_load_lds((const __attribute__((address_space(1))) void*)(src), \
                                   (__attribute__((address_space(3))) void*)(dst), 16, 0, 0)

// ---------------------------------------------------------------------------
// Kernel 0: zero A (8 MB, 16B/thread) + convert W2->bf16 + pre-scale W1,b1 by
// -log2(e) so the MLP inner loop feeds v_exp_f32 (2^t' = e^-t) directly.
// ---------------------------------------------------------------------------
__global__ void prep_zero(const float* __restrict__ W2, const float* __restrict__ W1,
                          const float* __restrict__ b1,
                          __hip_bfloat16* __restrict__ W2b,
                          float* __restrict__ W1n, float* __restrict__ b1n,
                          uint4v* __restrict__ A4) {
  const int t = blockIdx.x * 256 + threadIdx.x;   // 2048*256 threads
  A4[t] = (uint4v){0u, 0u, 0u, 0u};
  const float c = -1.4426950408889634f;  // -log2(e)
  if (t < 4096) W2b[t] = __float2bfloat16(W2[t]);
  if (t < 256)  W1n[t] = W1[t] * c;
  if (t < 128)  b1n[t] = b1[t] * c;
}

// ---------------------------------------------------------------------------
// Kernel 1: build A = K^T (bf16) with MFMA layer-2.  1D triangular grid:
// block t -> (bi <= bj), 16(i) x 16(j) pair tile, 4 waves, wave w owns
// j = j0+4w..j0+4w+3.  Lane l computes h for its own A-frag slots
// {row=l&15, k=(l>>4)*8+e}.  Inner loop: packed-f32 fma/add; bf16 pack via
// round-half-up + v_perm (round-4-verified).
// ---------------------------------------------------------------------------
__global__ __launch_bounds__(256) void build_A_mfma(
    const float* __restrict__ x,
    const float* __restrict__ W1n,             // [128][2], pre-scaled -log2e
    const float* __restrict__ b1n,             // [128],    pre-scaled -log2e
    const __hip_bfloat16* __restrict__ W2b,    // [32][128] bf16
    const float* __restrict__ b2,              // [32]
    const float* __restrict__ W3,              // [32]
    const float* __restrict__ b3,              // [1]
    __hip_bfloat16* __restrict__ A)            // [N][N], A[j][i]
{
  // decode linear upper-tri block id: t = bj*(bj+1)/2 + bi, bi <= bj
  const int t = blockIdx.x;
  int bj = (int)((sqrtf(8.0f * (float)t + 1.0f) - 1.0f) * 0.5f);
  while ((bj + 1) * (bj + 2) / 2 <= t) ++bj;
  while (bj * (bj + 1) / 2 > t) --bj;
  const int bi = t - bj * (bj + 1) / 2;

  const int i0 = bi * 16, j0 = bj * 16;
  const int tid = threadIdx.x;

  __shared__ float w1s[256];   // [k][2] pre-scaled
  __shared__ float b1s[128];
  w1s[tid] = W1n[tid & 255];
  if (tid < 128) b1s[tid] = b1n[tid];
  __syncthreads();

  const int w  = tid >> 6;
  const int l  = tid & 63;
  const int lm = l & 15;       // A-frag row (i-slot) / C col (o)
  const int lk = l >> 4;       // k-block-of-8 / C row-group

  const float xi = x[i0 + lm];
  float xj[4];
#pragma unroll
  for (int m = 0; m < 4; ++m) xj[m] = x[j0 + w * 4 + m];

  // W2 fragments (B^T row-major): lane holds W2[o=g*16+lm][kb*32+lk*8 .. +7]
  short8 wf[2][4];
#pragma unroll
  for (int g = 0; g < 2; ++g)
#pragma unroll
    for (int kb = 0; kb < 4; ++kb)
      wf[g][kb] = *(const short8*)(W2b + (g * 16 + lm) * 128 + kb * 32 + lk * 8);

  const float b2v[2] = {b2[lm], b2[16 + lm]};
  f32x4 acc[4][2];
#pragma unroll
  for (int m = 0; m < 4; ++m)
#pragma unroll
    for (int g = 0; g < 2; ++g)
      acc[m][g] = (f32x4){b2v[g], b2v[g], b2v[g], b2v[g]};

#pragma unroll
  for (int kb = 0; kb < 4; ++kb) {
    // xi-dependent half of layer 1, shared across the 4 j's of this wave-slot
    f32x2 basep[4], w1bp[4];
#pragma unroll
    for (int e2 = 0; e2 < 4; ++e2) {
      const int k = kb * 32 + lk * 8 + e2 * 2;
      basep[e2] = (f32x2){fmaf(w1s[2 * k],     xi, b1s[k]),
                          fmaf(w1s[2 * k + 2], xi, b1s[k + 1])};
      w1bp[e2]  = (f32x2){w1s[2 * k + 1], w1s[2 * k + 3]};
    }
#pragma unroll
    for (int m = 0; m < 4; ++m) {
      const f32x2 xj2 = (f32x2){xj[m], xj[m]};
      uint4v pk;
#pragma unroll
      for (int e2 = 0; e2 < 4; ++e2) {
        // h = sigmoid(t_orig) = 1/(1 + 2^t'),  t' = -log2e * t_orig
        const f32x2 t01 = __builtin_elementwise_fma(w1bp[e2], xj2, basep[e2]); // v_pk_fma_f32
        f32x2 e01;
        e01[0] = __builtin_amdgcn_exp2f(t01[0]);
        e01[1] = __builtin_amdgcn_exp2f(t01[1]);
        const f32x2 d01 = e01 + (f32x2){1.0f, 1.0f};                           // v_pk_add_f32
        const float h0 = __builtin_amdgcn_rcpf(d01[0]);   // t'->+inf: rcp(inf)=0 OK
        const float h1 = __builtin_amdgcn_rcpf(d01[1]);
        // round-4-verified bf16 pack: round-half-up + perm -> [hi16(u1)|hi16(u0)]
        const unsigned u0 = __builtin_bit_cast(unsigned, h0) + 0x8000u;
        const unsigned u1 = __builtin_bit_cast(unsigned, h1) + 0x8000u;
        pk[e2] = __builtin_amdgcn_perm(u1, u0, 0x07060302u);
      }
      const short8 af = __builtin_bit_cast(short8, pk);
      acc[m][0] = __builtin_amdgcn_mfma_f32_16x16x32_bf16(af, wf[0][kb], acc[m][0], 0, 0, 0);
      acc[m][1] = __builtin_amdgcn_mfma_f32_16x16x32_bf16(af, wf[1][kb], acc[m][1], 0, 0, 0);
    }
  }

  // Epilogue: v = b3 + sum_o relu(layer2[pair][o]) * W3[o]
  // C/D: row(pair) = lk*4 + r, col(o) = lm (+16 for g=1)
  const float w3a = W3[lm], w3b = W3[16 + lm];
  const float b3v = b3[0];
  const int   rsel = l & 3;

#pragma unroll
  for (int m = 0; m < 4; ++m) {
    const int j = j0 + w * 4 + m;
    float v[4];
#pragma unroll
    for (int r = 0; r < 4; ++r) {
      float s = fmaf(fmaxf(acc[m][0][r], 0.0f), w3a,
                     fmaxf(acc[m][1][r], 0.0f) * w3b);
      s += __shfl_xor(s, 1);
      s += __shfl_xor(s, 2);
      s += __shfl_xor(s, 4);
      s += __shfl_xor(s, 8);
      v[r] = s + b3v;
    }
    const float sv = rsel == 0 ? v[0] : rsel == 1 ? v[1] : rsel == 2 ? v[2] : v[3];
    const int i = i0 + lk * 4 + rsel;
    if (lm < 4 && i <= j)
      A[(size_t)j * N + i] = __float2bfloat16(sv);
  }
}

// ---------------------------------------------------------------------------
// Kernel 2: C = A * A^T  (NT GEMM, both operands = A, row-major bf16).
// 128x128 tile, BK=32, 4 waves (2x2), 16x16x32 MFMA, global_load_lds w=16.
// Guide-verified minimum 2-phase double-buffer (T3, m230): issue STAGE(kt+1)
// into buf^1, then read+MFMA buf[cur], then ONE __syncthreads per k-step
// (implies vmcnt(0)+lgkmcnt(0)+s_barrier -- compiler-fenced, race-free:
// the buffer STAGE targets was fully read by all waves before the PREVIOUS
// barrier).  Prefetch overlaps the ds_read+MFMA phase.
// Grid 16x16 = 256 blocks = 1/CU; triangular A -> k-clip at min(m0,n0)+128.
// ---------------------------------------------------------------------------
__global__ __launch_bounds__(256) void gemm_ata(
    const __hip_bfloat16* __restrict__ A, float* __restrict__ C)
{
  __shared__ __align__(16) __hip_bfloat16 As[2][128 * 32];  // 2 x 8 KB
  __shared__ __align__(16) __hip_bfloat16 Bs[2][128 * 32];  // 2 x 8 KB

  const int m0 = blockIdx.y * 128;
  const int n0 = blockIdx.x * 128;
  const int tid = threadIdx.x;
  const int w  = tid >> 6;
  const int l  = tid & 63;
  const int wr = (w >> 1) * 64;
  const int wc = (w & 1) * 64;
  const int lm = l & 15;
  const int lk = l >> 4;

  f32x4 acc[4][4];
#pragma unroll
  for (int m = 0; m < 4; ++m)
#pragma unroll
    for (int n = 0; n < 4; ++n)
      acc[m][n] = (f32x4){0.f, 0.f, 0.f, 0.f};

  const int mn = m0 < n0 ? m0 : n0;
  const int ktiles = (mn + 128) >> 5;   // nonzero k <= min(m0,n0)+127

  const int srow = l >> 2;          // 0..15
  const int scol = (l & 3) * 8;     // element offset (8 bf16 = 16B)

#define STAGE(kt, b)                                                                   \
  {                                                                                    \
    const int k0_ = (kt) * 32;                                                         \
    _Pragma("unroll")                                                                  \
    for (int c = 0; c < 2; ++c) {                                                      \
      const int r0 = (w * 2 + c) * 16;                                                 \
      GLOAD_LDS16(&As[b][r0 * 32], A + (size_t)(m0 + r0 + srow) * N + k0_ + scol);     \
      GLOAD_LDS16(&Bs[b][r0 * 32], A + (size_t)(n0 + r0 + srow) * N + k0_ + scol);     \
    }                                                                                  \
  }

  STAGE(0, 0);
  __syncthreads();   // vmcnt(0)+barrier: tile 0 staged

  for (int kt = 0; kt < ktiles; ++kt) {
    const int cur = kt & 1;
    if (kt + 1 < ktiles)
      STAGE(kt + 1, cur ^ 1);   // prefetch next tile; lands by the syncthreads below

    short8 af[4], bfr[4];
#pragma unroll
    for (int m = 0; m < 4; ++m)
      af[m] = *(const short8*)(&As[cur][(wr + m * 16 + lm) * 32 + lk * 8]);
#pragma unroll
    for (int n = 0; n < 4; ++n)
      bfr[n] = *(const short8*)(&Bs[cur][(wc + n * 16 + lm) * 32 + lk * 8]);

#pragma unroll
    for (int m = 0; m < 4; ++m)
#pragma unroll
      for (int n = 0; n < 4; ++n)
        acc[m][n] = __builtin_amdgcn_mfma_f32_16x16x32_bf16(af[m], bfr[n], acc[m][n], 0, 0, 0);

    __syncthreads();   // drains vmcnt (prefetch landed) + all waves done reading cur
  }
#undef STAGE

  // C/D layout: col = lane&15, row = (lane>>4)*4 + reg
#pragma unroll
  for (int m = 0; m < 4; ++m) {
    const int row = m0 + wr + m * 16 + lk * 4;
#pragma unroll
    for (int n = 0; n < 4; ++n) {
      const int col = n0 + wc + n * 16 + lm;
#pragma unroll
      for (int r = 0; r < 4; ++r)
        C[(size_t)(row + r) * N + col] = acc[m][n][r];
    }
  }
}

// ---------------------------------------------------------------------------
extern "C" void kernel_launch(void* const* d_in, const int* in_sizes, int n_in,
                              void* d_out, int out_size, void* d_ws, size_t ws_size,
                              hipStream_t stream) {
  const float* x  = (const float*)d_in[0];
  const float* W1 = (const float*)d_in[1];
  const float* b1 = (const float*)d_in[2];
  const float* W2 = (const float*)d_in[3];
  const float* b2 = (const float*)d_in[4];
  const float* W3 = (const float*)d_in[5];
  const float* b3 = (const float*)d_in[6];
  float* C = (float*)d_out;

  // ws: [0,8K) W2b bf16; [8K,9K) W1n; [12K,12.5K) b1n; [16K,16K+8M) A bf16
  __hip_bfloat16* W2b = (__hip_bfloat16*)d_ws;
  float* W1n = (float*)((char*)d_ws + 8192);
  float* b1n = (float*)((char*)d_ws + 12288);
  __hip_bfloat16* A = (__hip_bfloat16*)((char*)d_ws + 16384);

  prep_zero<<<dim3(2048), dim3(256), 0, stream>>>(W2, W1, b1, W2b, W1n, b1n, (uint4v*)A);
  build_A_mfma<<<dim3(8256), dim3(256), 0, stream>>>(x, W1n, b1n, W2b, b2, W3, b3, A);
  gemm_ata<<<dim3(16, 16), dim3(256), 0, stream>>>(A, C);
}

// Round 9
// 180.803 us; speedup vs baseline: 1.0130x; 1.0130x over previous
//
#include <hip/hip_runtime.h>
#include <hip/hip_bf16.h>

#define N 2048

using f32x2  = __attribute__((ext_vector_type(2))) float;
using f32x4  = __attribute__((ext_vector_type(4))) float;
using short8 = __attribute__((ext_vector_type(8))) short;

// async global->LDS, 16B per lane; LDS dest = wave-uniform base + lane*16
#define GLOAD_LDS16(dst, src)                                                        \
  __builtin_amdgcn_global_load_lds((const __attribute__((address_space(1))) void*)(src), \
                                   (__attribute__((address_space(3))) void*)(dst), 16, 0, 0)

// ---------------------------------------------------------------------------
// Kernel 0: weights-only prep (1 block).  W2 -> bf16 [32][128]; W1,b1 pre-
// scaled by -log2(e) so the MLP inner loop feeds v_exp_f32 (2^t' = e^-t).
// NOTE: A is NOT zeroed anywhere globally -- the gemm's triangular k-clip
// only ever reads lower-triangle elements inside the 16 within-panel
// diagonal bands, which build_A's zero-blocks + diagonal blocks cover.
// ---------------------------------------------------------------------------
__global__ void prep_w(const float* __restrict__ W2, const float* __restrict__ W1,
                       const float* __restrict__ b1,
                       __hip_bfloat16* __restrict__ W2b,
                       float* __restrict__ W1n, float* __restrict__ b1n) {
  const int tid = threadIdx.x;   // 256 threads
  const float c = -1.4426950408889634f;  // -log2(e)
#pragma unroll
  for (int q = 0; q < 16; ++q)
    W2b[q * 256 + tid] = __float2bfloat16(W2[q * 256 + tid]);
  W1n[tid] = W1[tid] * c;
  if (tid < 128) b1n[tid] = b1[tid] * c;
}

// ---------------------------------------------------------------------------
// Kernel 1: build A = K^T (bf16) with MFMA layer-2.
// Grid 8704: t < 8256 -> upper-tri MLP block (bi <= bj, 16x16 pair tile);
// t >= 8256 -> band-zero block (within-panel strictly-lower 16x16 tile,
// 448 = 16 panels x C(8,2)).  Diagonal MLP blocks (bi==bj) write zeros for
// their i > j half.  Inner loop identical to round-7 (verified).
// ---------------------------------------------------------------------------
__global__ __launch_bounds__(256) void build_A_mfma(
    const float* __restrict__ x,
    const float* __restrict__ W1n,             // [128][2], pre-scaled -log2e
    const float* __restrict__ b1n,             // [128],    pre-scaled -log2e
    const __hip_bfloat16* __restrict__ W2b,    // [32][128] bf16
    const float* __restrict__ b2,              // [32]
    const float* __restrict__ W3,              // [32]
    const float* __restrict__ b3,              // [1]
    __hip_bfloat16* __restrict__ A)            // [N][N], A[j][i]
{
  const int t = blockIdx.x;
  const int tid = threadIdx.x;

  if (t >= 8256) {               // band-zero block
    const int z = t - 8256;      // 0..447
    const int p = z / 28, q = z % 28;
    int r = 1;                    // decode strict lower-tri pair (r > c) from q
    while ((r * (r + 1)) / 2 <= q) ++r;       // r in 1..7
    const int c2 = q - (r * (r - 1)) / 2;     // c in 0..r-1
    const int jj = (p * 8 + c2) * 16 + (tid >> 4);   // row j (block bj = c2 < r)
    const int ii = (p * 8 + r) * 16 + (tid & 15);    // col i (block bi = r)
    A[(size_t)jj * N + ii] = __float2bfloat16(0.0f); // i > j here always
    return;
  }

  // decode linear upper-tri block id: t = bj*(bj+1)/2 + bi, bi <= bj
  int bj = (int)((sqrtf(8.0f * (float)t + 1.0f) - 1.0f) * 0.5f);
  while ((bj + 1) * (bj + 2) / 2 <= t) ++bj;
  while (bj * (bj + 1) / 2 > t) --bj;
  const int bi = t - bj * (bj + 1) / 2;

  const int i0 = bi * 16, j0 = bj * 16;

  __shared__ float w1s[256];   // [k][2] pre-scaled
  __shared__ float b1s[128];
  w1s[tid] = W1n[tid & 255];
  if (tid < 128) b1s[tid] = b1n[tid];
  __syncthreads();

  const int w  = tid >> 6;
  const int l  = tid & 63;
  const int lm = l & 15;       // A-frag row (i-slot) / C col (o)
  const int lk = l >> 4;       // k-block-of-8 / C row-group

  const float xi = x[i0 + lm];
  float xj[4];
#pragma unroll
  for (int m = 0; m < 4; ++m) xj[m] = x[j0 + w * 4 + m];

  // W2 fragments (B^T row-major): lane holds W2[o=g*16+lm][kb*32+lk*8 .. +7]
  short8 wf[2][4];
#pragma unroll
  for (int g = 0; g < 2; ++g)
#pragma unroll
    for (int kb = 0; kb < 4; ++kb)
      wf[g][kb] = *(const short8*)(W2b + (g * 16 + lm) * 128 + kb * 32 + lk * 8);

  const float b2v[2] = {b2[lm], b2[16 + lm]};
  f32x4 acc[4][2];
#pragma unroll
  for (int m = 0; m < 4; ++m)
#pragma unroll
    for (int g = 0; g < 2; ++g)
      acc[m][g] = (f32x4){b2v[g], b2v[g], b2v[g], b2v[g]};

#pragma unroll
  for (int kb = 0; kb < 4; ++kb) {
    // xi-dependent half of layer 1, shared across the 4 j's of this wave-slot
    f32x2 basep[4], w1bp[4];
#pragma unroll
    for (int e2 = 0; e2 < 4; ++e2) {
      const int k = kb * 32 + lk * 8 + e2 * 2;
      basep[e2] = (f32x2){fmaf(w1s[2 * k],     xi, b1s[k]),
                          fmaf(w1s[2 * k + 2], xi, b1s[k + 1])};
      w1bp[e2]  = (f32x2){w1s[2 * k + 1], w1s[2 * k + 3]};
    }
#pragma unroll
    for (int m = 0; m < 4; ++m) {
      const f32x2 xj2 = (f32x2){xj[m], xj[m]};
      __attribute__((ext_vector_type(4))) unsigned pk;
#pragma unroll
      for (int e2 = 0; e2 < 4; ++e2) {
        // h = sigmoid(t_orig) = 1/(1 + 2^t'),  t' = -log2e * t_orig
        const f32x2 t01 = __builtin_elementwise_fma(w1bp[e2], xj2, basep[e2]); // v_pk_fma_f32
        f32x2 e01;
        e01[0] = __builtin_amdgcn_exp2f(t01[0]);
        e01[1] = __builtin_amdgcn_exp2f(t01[1]);
        const f32x2 d01 = e01 + (f32x2){1.0f, 1.0f};                           // v_pk_add_f32
        const float h0 = __builtin_amdgcn_rcpf(d01[0]);   // t'->+inf: rcp(inf)=0 OK
        const float h1 = __builtin_amdgcn_rcpf(d01[1]);
        // round-half-up + perm -> [hi16(u1)|hi16(u0)]  (round-4-verified pack)
        const unsigned u0 = __builtin_bit_cast(unsigned, h0) + 0x8000u;
        const unsigned u1 = __builtin_bit_cast(unsigned, h1) + 0x8000u;
        pk[e2] = __builtin_amdgcn_perm(u1, u0, 0x07060302u);
      }
      const short8 af = __builtin_bit_cast(short8, pk);
      acc[m][0] = __builtin_amdgcn_mfma_f32_16x16x32_bf16(af, wf[0][kb], acc[m][0], 0, 0, 0);
      acc[m][1] = __builtin_amdgcn_mfma_f32_16x16x32_bf16(af, wf[1][kb], acc[m][1], 0, 0, 0);
    }
  }

  // Epilogue: v = b3 + sum_o relu(layer2[pair][o]) * W3[o]
  // C/D: row(pair) = lk*4 + r, col(o) = lm (+16 for g=1)
  const float w3a = W3[lm], w3b = W3[16 + lm];
  const float b3v = b3[0];
  const int   rsel = l & 3;

#pragma unroll
  for (int m = 0; m < 4; ++m) {
    const int j = j0 + w * 4 + m;
    float v[4];
#pragma unroll
    for (int r = 0; r < 4; ++r) {
      float s = fmaf(fmaxf(acc[m][0][r], 0.0f), w3a,
                     fmaxf(acc[m][1][r], 0.0f) * w3b);
      s += __shfl_xor(s, 1);
      s += __shfl_xor(s, 2);
      s += __shfl_xor(s, 4);
      s += __shfl_xor(s, 8);
      v[r] = s + b3v;
    }
    const float sv = rsel == 0 ? v[0] : rsel == 1 ? v[1] : rsel == 2 ? v[2] : v[3];
    const int i = i0 + lk * 4 + rsel;
    // bi<bj: i<j always (store sv).  bi==bj: store sv for i<=j, 0 for i>j
    // (covers the diagonal block's upper-right half -- no global zeroing).
    if (lm < 4)
      A[(size_t)j * N + i] = __float2bfloat16(i <= j ? sv : 0.0f);
  }
}

// ---------------------------------------------------------------------------
// Kernel 2: C = A * A^T  (NT GEMM, both operands = A, row-major bf16).
// BYTE-IDENTICAL to round-7 (passed): 128x128 tile, BK=32, 4 waves, 16x16x32
// MFMA, global_load_lds w=16, 2-phase double-buffer with ONE __syncthreads
// per k-step (compiler-fenced).  Triangular k-clip at min(m0,n0)+128.
// ---------------------------------------------------------------------------
__global__ __launch_bounds__(256) void gemm_ata(
    const __hip_bfloat16* __restrict__ A, float* __restrict__ C)
{
  __shared__ __align__(16) __hip_bfloat16 As[2][128 * 32];  // 2 x 8 KB
  __shared__ __align__(16) __hip_bfloat16 Bs[2][128 * 32];  // 2 x 8 KB

  const int m0 = blockIdx.y * 128;
  const int n0 = blockIdx.x * 128;
  const int tid = threadIdx.x;
  const int w  = tid >> 6;
  const int l  = tid & 63;
  const int wr = (w >> 1) * 64;
  const int wc = (w & 1) * 64;
  const int lm = l & 15;
  const int lk = l >> 4;

  f32x4 acc[4][4];
#pragma unroll
  for (int m = 0; m < 4; ++m)
#pragma unroll
    for (int n = 0; n < 4; ++n)
      acc[m][n] = (f32x4){0.f, 0.f, 0.f, 0.f};

  const int mn = m0 < n0 ? m0 : n0;
  const int ktiles = (mn + 128) >> 5;   // nonzero k <= min(m0,n0)+127

  const int srow = l >> 2;          // 0..15
  const int scol = (l & 3) * 8;     // element offset (8 bf16 = 16B)

#define STAGE(kt, b)                                                                   \
  {                                                                                    \
    const int k0_ = (kt) * 32;                                                         \
    _Pragma("unroll")                                                                  \
    for (int c = 0; c < 2; ++c) {                                                      \
      const int r0 = (w * 2 + c) * 16;                                                 \
      GLOAD_LDS16(&As[b][r0 * 32], A + (size_t)(m0 + r0 + srow) * N + k0_ + scol);     \
      GLOAD_LDS16(&Bs[b][r0 * 32], A + (size_t)(n0 + r0 + srow) * N + k0_ + scol);     \
    }                                                                                  \
  }

  STAGE(0, 0);
  __syncthreads();   // vmcnt(0)+barrier: tile 0 staged

  for (int kt = 0; kt < ktiles; ++kt) {
    const int cur = kt & 1;
    if (kt + 1 < ktiles)
      STAGE(kt + 1, cur ^ 1);   // prefetch next tile; lands by the syncthreads below

    short8 af[4], bfr[4];
#pragma unroll
    for (int m = 0; m < 4; ++m)
      af[m] = *(const short8*)(&As[cur][(wr + m * 16 + lm) * 32 + lk * 8]);
#pragma unroll
    for (int n = 0; n < 4; ++n)
      bfr[n] = *(const short8*)(&Bs[cur][(wc + n * 16 + lm) * 32 + lk * 8]);

#pragma unroll
    for (int m = 0; m < 4; ++m)
#pragma unroll
      for (int n = 0; n < 4; ++n)
        acc[m][n] = __builtin_amdgcn_mfma_f32_16x16x32_bf16(af[m], bfr[n], acc[m][n], 0, 0, 0);

    __syncthreads();   // drains vmcnt (prefetch landed) + all waves done reading cur
  }
#undef STAGE

  // C/D layout: col = lane&15, row = (lane>>4)*4 + reg
#pragma unroll
  for (int m = 0; m < 4; ++m) {
    const int row = m0 + wr + m * 16 + lk * 4;
#pragma unroll
    for (int n = 0; n < 4; ++n) {
      const int col = n0 + wc + n * 16 + lm;
#pragma unroll
      for (int r = 0; r < 4; ++r)
        C[(size_t)(row + r) * N + col] = acc[m][n][r];
    }
  }
}

// ---------------------------------------------------------------------------
extern "C" void kernel_launch(void* const* d_in, const int* in_sizes, int n_in,
                              void* d_out, int out_size, void* d_ws, size_t ws_size,
                              hipStream_t stream) {
  const float* x  = (const float*)d_in[0];
  const float* W1 = (const float*)d_in[1];
  const float* b1 = (const float*)d_in[2];
  const float* W2 = (const float*)d_in[3];
  const float* b2 = (const float*)d_in[4];
  const float* W3 = (const float*)d_in[5];
  const float* b3 = (const float*)d_in[6];
  float* C = (float*)d_out;

  // ws: [0,8K) W2b bf16; [8K,9K) W1n; [12K,12.5K) b1n; [16K,16K+8M) A bf16
  __hip_bfloat16* W2b = (__hip_bfloat16*)d_ws;
  float* W1n = (float*)((char*)d_ws + 8192);
  float* b1n = (float*)((char*)d_ws + 12288);
  __hip_bfloat16* A = (__hip_bfloat16*)((char*)d_ws + 16384);

  prep_w<<<dim3(1), dim3(256), 0, stream>>>(W2, W1, b1, W2b, W1n, b1n);
  build_A_mfma<<<dim3(8704), dim3(256), 0, stream>>>(x, W1n, b1n, W2b, b2, W3, b3, A);
  gemm_ata<<<dim3(16, 16), dim3(256), 0, stream>>>(A, C);
}